// Round 1
// baseline (9597.067 us; speedup 1.0000x reference)
//
#include <hip/hip_runtime.h>
#include <math.h>

// Problem constants: B=8, S=16, CIN=128, H=W=64, D=64
// N = B*S = 128 conv-batch, P = H*W = 4096 spatial

__device__ __forceinline__ float sigf(float x){ return 1.0f/(1.0f + expf(-x)); }

#define FMA4(A, W, V0, V1, V2, V3) { (A).x += (W)*(V0); (A).y += (W)*(V1); (A).z += (W)*(V2); (A).w += (W)*(V3); }

// ---------------------------------------------------------------------------
// reshape clstm_w (256,128,3,3) -> w2[(ic*9+k)*256 + oc]
__global__ __launch_bounds__(256) void k_w2(const float* __restrict__ cw, float* __restrict__ w2){
    int idx = blockIdx.x*256 + threadIdx.x;
    if (idx < 128*9*256){
        int oc = idx & 255;
        int r  = idx >> 8;           // r = ic*9 + k
        w2[idx] = cw[oc*1152 + r];
    }
}

// ---------------------------------------------------------------------------
// 1x1 proj conv + BN partial sums. Writes raw t==0 slice into x0 buffer.
// grid (16 tiles, 128 n), block 256. Thread: 4 px (float4) x 16 d.
__global__ __launch_bounds__(256) void k_proj(const float* __restrict__ x, const float* __restrict__ pw,
                                              float* __restrict__ x0raw, float* __restrict__ psum,
                                              float* __restrict__ psumsq){
    __shared__ __align__(16) float smem[8192];   // w_lds[c][64], later reduction scratch
    const int tile = blockIdx.x;
    const int n    = blockIdx.y;
    const int tid  = threadIdx.x;
    const int pj = tid & 63, dg = tid >> 6;

    for (int r = tid; r < 8192; r += 256){
        int c = r >> 6, d = r & 63;
        smem[r] = pw[d*128 + c];
    }
    __syncthreads();

    const int p0 = tile*256 + pj*4;
    float4 acc[16];
#pragma unroll
    for (int i=0;i<16;i++) acc[i] = make_float4(0.f,0.f,0.f,0.f);

    const float* xb = x + (((size_t)n) << 19) + p0;
    for (int c = 0; c < 128; ++c){
        float4 xv = *(const float4*)(xb + ((size_t)c << 12));
        const float4* wr = (const float4*)(smem + c*64 + dg*16);
#pragma unroll
        for (int q=0;q<4;++q){
            float4 w4 = wr[q];
            FMA4(acc[q*4+0], w4.x, xv.x, xv.y, xv.z, xv.w);
            FMA4(acc[q*4+1], w4.y, xv.x, xv.y, xv.z, xv.w);
            FMA4(acc[q*4+2], w4.z, xv.x, xv.y, xv.z, xv.w);
            FMA4(acc[q*4+3], w4.w, xv.x, xv.y, xv.z, xv.w);
        }
    }

    const int t = n & 15, b = n >> 4;
    if (t == 0){
#pragma unroll
        for (int i=0;i<16;i++){
            int dd = dg*16 + i;
            *(float4*)(x0raw + (((size_t)(b*64 + dd)) << 12) + p0) = acc[i];
        }
    }
    float ls[16], lss[16];
#pragma unroll
    for (int i=0;i<16;i++){
        float4 a = acc[i];
        ls[i]  = a.x + a.y + a.z + a.w;
        lss[i] = a.x*a.x + a.y*a.y + a.z*a.z + a.w*a.w;
    }
    // deterministic block reduction (pad 65 to avoid bank conflicts)
    __syncthreads();
#pragma unroll
    for (int i=0;i<16;i++) smem[pj*65 + dg*16 + i] = ls[i];
    __syncthreads();
    if (tid < 64){
        float s = 0.f;
        for (int p=0;p<64;p++) s += smem[p*65 + tid];
        psum[((n*16 + tile) << 6) + tid] = s;
    }
    __syncthreads();
#pragma unroll
    for (int i=0;i<16;i++) smem[pj*65 + dg*16 + i] = lss[i];
    __syncthreads();
    if (tid < 64){
        float s = 0.f;
        for (int p=0;p<64;p++) s += smem[p*65 + tid];
        psumsq[((n*16 + tile) << 6) + tid] = s;
    }
}

// ---------------------------------------------------------------------------
// BN finalize: scale/shift per d (fp64 accumulate), and xmean[b][t][d].
__global__ __launch_bounds__(64) void k_bnfinal(const float* __restrict__ psum, const float* __restrict__ psumsq,
                                                const float* __restrict__ gamma, const float* __restrict__ beta,
                                                float* __restrict__ scale, float* __restrict__ shift,
                                                float* __restrict__ xmean){
    const int d = threadIdx.x;
    double gs = 0.0, gss = 0.0;
    for (int n=0;n<128;n++){
        float s = 0.f, ss = 0.f;
        for (int tl=0;tl<16;tl++){
            s  += psum  [((n*16+tl)<<6) + d];
            ss += psumsq[((n*16+tl)<<6) + d];
        }
        gs += (double)s; gss += (double)ss;
    }
    double mu  = gs  / 524288.0;
    double var = gss / 524288.0 - mu*mu;
    double sc  = (double)gamma[d] / sqrt(var + 1e-5);
    float scf = (float)sc;
    float shf = (float)((double)beta[d] - mu*sc);
    scale[d] = scf; shift[d] = shf;
    for (int n=0;n<128;n++){
        float s = 0.f;
        for (int tl=0;tl<16;tl++) s += psum[((n*16+tl)<<6) + d];
        xmean[(n<<6) + d] = (s * (1.f/4096.f)) * scf + shf;
    }
}

// ---------------------------------------------------------------------------
// Apply BN to x0 (in place), init yhat=x0, hfA=0, cf=0, states=0, P=P_init.
__global__ __launch_bounds__(256) void k_init(const float* __restrict__ scale, const float* __restrict__ shift,
                                              float* __restrict__ x0, float* __restrict__ yhat,
                                              float* __restrict__ hfA, float* __restrict__ cf,
                                              const float* __restrict__ Pinit, float* __restrict__ Pg,
                                              float* __restrict__ hQ, float* __restrict__ cQ,
                                              float* __restrict__ hR, float* __restrict__ cR){
    size_t idx = (size_t)blockIdx.x*256 + threadIdx.x;   // 2,097,152 total
    int d = (int)((idx >> 12) & 63);
    float v = x0[idx]*scale[d] + shift[d];
    x0[idx] = v; yhat[idx] = v; hfA[idx] = 0.f; cf[idx] = 0.f;
    if (idx < 512){ hQ[idx]=0.f; cQ[idx]=0.f; hR[idx]=0.f; cR[idx]=0.f; }
    if (idx < 32768) Pg[idx] = Pinit[idx & 4095];
}

// ---------------------------------------------------------------------------
// ConvLSTM step: zc = conv3x3([yhat, hf_in]) + b; gates -> cf (in place), hf_out.
// grid (64 rows, 8 b), block 256. smem: 64KB union {w[4][9][256]+in[4][3][66] | zc[64px][256oc]}.
__global__ __launch_bounds__(256) void k_conv(const float* __restrict__ yhat, const float* __restrict__ hf_in,
                                              float* __restrict__ hf_out, float* __restrict__ cf,
                                              const float* __restrict__ w2, const float* __restrict__ cb,
                                              float* __restrict__ hfpart){
    __shared__ __align__(16) float smem[16384];
    const int row = blockIdx.x;
    const int b   = blockIdx.y;
    const int tid = threadIdx.x;
    const int pxq = tid & 15;     // 4 px each
    const int ocq = tid >> 4;     // 16 oc each
    const int IN_OFF = 9216;

    float4 acc[16];
#pragma unroll
    for (int i=0;i<16;i++) acc[i] = make_float4(0.f,0.f,0.f,0.f);

    for (int icc = 0; icc < 32; ++icc){
        __syncthreads();
        {   // stage 4 ic of weights: contiguous copy, [icl][k][oc]
            const float4* src = (const float4*)(w2 + (size_t)icc*9216);
            float4* dst = (float4*)(smem);
            for (int r = tid; r < 2304; r += 256) dst[r] = src[r];
        }
        for (int r = tid; r < 792; r += 256){   // 4 ic x 3 dy x 66 xi
            int icl = r / 198; int rem = r - icl*198;
            int dy  = rem / 66; int xi = rem - dy*66;
            int icg = icc*4 + icl;
            int yy = row + dy - 1;
            int xx = xi - 1;
            float v = 0.f;
            if (yy >= 0 && yy < 64 && xx >= 0 && xx < 64){
                const float* src = (icg < 64) ? yhat : hf_in;
                v = src[(((size_t)(b*64 + (icg & 63))) << 12) + yy*64 + xx];
            }
            smem[IN_OFF + r] = v;
        }
        __syncthreads();
#pragma unroll
        for (int icl = 0; icl < 4; ++icl){
            float v[3][6];
#pragma unroll
            for (int dy=0; dy<3; ++dy)
#pragma unroll
                for (int j=0;j<6;++j)
                    v[dy][j] = smem[IN_OFF + icl*198 + dy*66 + pxq*4 + j];
#pragma unroll
            for (int k=0;k<9;++k){
                const int ky = k/3, kx = k - ky*3;
                const float4* wr = (const float4*)(smem + (icl*9+k)*256 + ocq*16);
                const float v0=v[ky][kx+0], v1=v[ky][kx+1], v2=v[ky][kx+2], v3=v[ky][kx+3];
#pragma unroll
                for (int q=0;q<4;++q){
                    float4 w4 = wr[q];
                    FMA4(acc[q*4+0], w4.x, v0,v1,v2,v3);
                    FMA4(acc[q*4+1], w4.y, v0,v1,v2,v3);
                    FMA4(acc[q*4+2], w4.z, v0,v1,v2,v3);
                    FMA4(acc[q*4+3], w4.w, v0,v1,v2,v3);
                }
            }
        }
    }

    // write zc (+bias) to LDS, layout [px][256 oc]
    __syncthreads();
#pragma unroll
    for (int i=0;i<16;i++){
        int oc = ocq*16 + i;
        float bv = cb[oc];
        int px0 = pxq*4;
        smem[(px0+0)*256 + oc] = acc[i].x + bv;
        smem[(px0+1)*256 + oc] = acc[i].y + bv;
        smem[(px0+2)*256 + oc] = acc[i].z + bv;
        smem[(px0+3)*256 + oc] = acc[i].w + bv;
    }
    __syncthreads();

    // gating: i,f,o,g order. thread: d = tid&63, 16 px.
    const int d   = tid & 63;
    const int pxg = tid >> 6;
    float hsum = 0.f;
#pragma unroll
    for (int jq=0; jq<4; ++jq){
        int px0 = pxg*16 + jq*4;
        float zi0 = smem[(px0+0)*256 + d],       zi1 = smem[(px0+1)*256 + d],       zi2 = smem[(px0+2)*256 + d],       zi3 = smem[(px0+3)*256 + d];
        float zf0 = smem[(px0+0)*256 + 64 + d],  zf1 = smem[(px0+1)*256 + 64 + d],  zf2 = smem[(px0+2)*256 + 64 + d],  zf3 = smem[(px0+3)*256 + 64 + d];
        float zo0 = smem[(px0+0)*256 + 128 + d], zo1 = smem[(px0+1)*256 + 128 + d], zo2 = smem[(px0+2)*256 + 128 + d], zo3 = smem[(px0+3)*256 + 128 + d];
        float zg0 = smem[(px0+0)*256 + 192 + d], zg1 = smem[(px0+1)*256 + 192 + d], zg2 = smem[(px0+2)*256 + 192 + d], zg3 = smem[(px0+3)*256 + 192 + d];
        size_t gidx = (((size_t)(b*64 + d)) << 12) + row*64 + px0;
        float4 c_old = *(const float4*)(cf + gidx);
        float4 c2, h;
        c2.x = sigf(zf0)*c_old.x + sigf(zi0)*tanhf(zg0); h.x = sigf(zo0)*tanhf(c2.x);
        c2.y = sigf(zf1)*c_old.y + sigf(zi1)*tanhf(zg1); h.y = sigf(zo1)*tanhf(c2.y);
        c2.z = sigf(zf2)*c_old.z + sigf(zi2)*tanhf(zg2); h.z = sigf(zo2)*tanhf(c2.z);
        c2.w = sigf(zf3)*c_old.w + sigf(zi3)*tanhf(zg3); h.w = sigf(zo3)*tanhf(c2.w);
        *(float4*)(cf + gidx) = c2;
        *(float4*)(hf_out + gidx) = h;
        hsum += h.x + h.y + h.z + h.w;
    }
    __syncthreads();
    smem[pxg*64 + d] = hsum;
    __syncthreads();
    if (tid < 64){
        float s = smem[tid] + smem[64+tid] + smem[128+tid] + smem[192+tid];
        hfpart[((b*64 + row) << 6) + tid] = s;
    }
}

// ---------------------------------------------------------------------------
// y_tick = fcf(hf) per position + spatial partial sums. grid (16,8), block 256.
__global__ __launch_bounds__(256) void k_ytick(const float* __restrict__ hf, const float* __restrict__ fw,
                                               const float* __restrict__ fb, float* __restrict__ ytick,
                                               float* __restrict__ ytpart){
    __shared__ __align__(16) float wsm[4096];
    __shared__ float red[4160];
    const int tile = blockIdx.x;
    const int b    = blockIdx.y;
    const int tid  = threadIdx.x;
    const int pj = tid & 63, dg = tid >> 6;

    for (int r = tid; r < 4096; r += 256){
        int e = r >> 6, dd = r & 63;
        wsm[r] = fw[dd*64 + e];
    }
    __syncthreads();

    const int p0 = tile*256 + pj*4;
    float4 acc[16];
#pragma unroll
    for (int i=0;i<16;i++) acc[i] = make_float4(0.f,0.f,0.f,0.f);

    const float* hb = hf + (((size_t)b) << 18) + p0;
    for (int e = 0; e < 64; ++e){
        float4 hv = *(const float4*)(hb + ((size_t)e << 12));
        const float4* wr = (const float4*)(wsm + e*64 + dg*16);
#pragma unroll
        for (int q=0;q<4;++q){
            float4 w4 = wr[q];
            FMA4(acc[q*4+0], w4.x, hv.x, hv.y, hv.z, hv.w);
            FMA4(acc[q*4+1], w4.y, hv.x, hv.y, hv.z, hv.w);
            FMA4(acc[q*4+2], w4.z, hv.x, hv.y, hv.z, hv.w);
            FMA4(acc[q*4+3], w4.w, hv.x, hv.y, hv.z, hv.w);
        }
    }
    float ls[16];
#pragma unroll
    for (int i=0;i<16;i++){
        int dd = dg*16 + i;
        float bv = fb[dd];
        acc[i].x += bv; acc[i].y += bv; acc[i].z += bv; acc[i].w += bv;
        *(float4*)(ytick + (((size_t)(b*64 + dd)) << 12) + p0) = acc[i];
        ls[i] = acc[i].x + acc[i].y + acc[i].z + acc[i].w;
    }
#pragma unroll
    for (int i=0;i<16;i++) red[pj*65 + dg*16 + i] = ls[i];
    __syncthreads();
    if (tid < 64){
        float s = 0.f;
        for (int p=0;p<64;p++) s += red[p*65 + tid];
        ytpart[((b*16 + tile) << 6) + tid] = s;
    }
}

// ---------------------------------------------------------------------------
// Per-step small ops + Kalman update. grid 8 (b), block 256.
__global__ __launch_bounds__(256) void k_small(int t,
        const float* __restrict__ hfpart, const float* __restrict__ ytpart, const float* __restrict__ xmean,
        const float* __restrict__ fcF_w, const float* __restrict__ fcF_b,
        const float* __restrict__ lq_wih, const float* __restrict__ lq_whh,
        const float* __restrict__ lq_bih, const float* __restrict__ lq_bhh,
        const float* __restrict__ lr_wih, const float* __restrict__ lr_whh,
        const float* __restrict__ lr_bih, const float* __restrict__ lr_bhh,
        const float* __restrict__ fcQ_w, const float* __restrict__ fcQ_b,
        const float* __restrict__ fcR_w, const float* __restrict__ fcR_b,
        float* __restrict__ hQ, float* __restrict__ cQ, float* __restrict__ hR, float* __restrict__ cR,
        float* __restrict__ Pg, float* __restrict__ Kg){
    const int b = blockIdx.x, tid = threadIdx.x;
    __shared__ __align__(16) float aug[64*132];
    __shared__ __align__(16) float Pl[4096];
    __shared__ float hfm[64], ytm[64], xm[64], Fv[64], Qd[64], Rd[64], rds[64];
    __shared__ float hq_s[64], cq_s[64], hr_s[64], cr_s[64];
    __shared__ float gq[256], gr[256];

    if (tid < 64){
        float s = 0.f;
        for (int r=0;r<64;r++) s += hfpart[((b*64 + r) << 6) + tid];
        hfm[tid] = s * (1.f/4096.f);
        float s2 = 0.f;
        for (int r=0;r<16;r++) s2 += ytpart[((b*16 + r) << 6) + tid];
        ytm[tid] = s2 * (1.f/4096.f);
        xm[tid] = xmean[((b*16 + t) << 6) + tid];
        hq_s[tid] = hQ[b*64+tid]; cq_s[tid] = cQ[b*64+tid];
        hr_s[tid] = hR[b*64+tid]; cr_s[tid] = cR[b*64+tid];
    }
    __syncthreads();
    {   // LSTM gate pre-activations (all 256 threads) + Fv (first 64)
        int j = tid;
        float aq = lq_bih[j] + lq_bhh[j];
        float ar = lr_bih[j] + lr_bhh[j];
        for (int e=0;e<64;e++){
            aq += lq_wih[j*64+e]*ytm[e] + lq_whh[j*64+e]*hq_s[e];
            ar += lr_wih[j*64+e]*xm[e]  + lr_whh[j*64+e]*hr_s[e];
        }
        gq[j] = aq; gr[j] = ar;
    }
    if (tid < 64){
        float a = fcF_b[tid];
        for (int e=0;e<64;e++) a += fcF_w[tid*64+e]*hfm[e];
        Fv[tid] = a;
    }
    __syncthreads();
    if (tid < 64){   // lstm_cell gate order: i, f, g, o
        int dd = tid;
        float gi = gq[dd], gf = gq[64+dd], gg = gq[128+dd], go = gq[192+dd];
        float c2 = sigf(gf)*cq_s[dd] + sigf(gi)*tanhf(gg);
        float h2 = sigf(go)*tanhf(c2);
        cq_s[dd] = c2; hq_s[dd] = h2;
        gi = gr[dd]; gf = gr[64+dd]; gg = gr[128+dd]; go = gr[192+dd];
        c2 = sigf(gf)*cr_s[dd] + sigf(gi)*tanhf(gg);
        h2 = sigf(go)*tanhf(c2);
        cr_s[dd] = c2; hr_s[dd] = h2;
    }
    __syncthreads();
    if (tid < 64){
        float aq_ = fcQ_b[tid], ar_ = fcR_b[tid];
        for (int e=0;e<64;e++){ aq_ += fcQ_w[tid*64+e]*hq_s[e]; ar_ += fcR_w[tid*64+e]*hr_s[e]; }
        Qd[tid] = expf(aq_); Rd[tid] = expf(ar_);
        hQ[b*64+tid] = hq_s[tid]; cQ[b*64+tid] = cq_s[tid];
        hR[b*64+tid] = hr_s[tid]; cR[b*64+tid] = cr_s[tid];
    }
    __syncthreads();
    // P = P*FF + diag(Qd); aug = [A=P+diag(Rd) | P]
    for (int r = tid; r < 4096; r += 256){
        int i = r >> 6, j = r & 63;
        float p = Pg[((size_t)b << 12) + r] * Fv[i]*Fv[j] + (i==j ? Qd[i] : 0.f);
        Pl[r] = p;
        aug[i*132 + 64 + j] = p;
        aug[i*132 + j]      = p + (i==j ? Rd[i] : 0.f);
    }
    __syncthreads();
    // Gauss-Jordan, no pivot-row scaling, only cols > k touched (race-free, 1 barrier/iter)
    const int r_ = tid & 63, cq_ = tid >> 6;
    for (int k = 0; k < 64; ++k){
        float akk = aug[k*132 + k];
        float f = aug[r_*132 + k] / akk;
        if (r_ != k){
#pragma unroll
            for (int u = 0; u < 8; ++u){
                int c4 = cq_*32 + u*4;
                if (c4 + 3 > k){
                    float4 pv = *(const float4*)(aug + k*132 + c4);
                    float4 av = *(const float4*)(aug + r_*132 + c4);
                    av.x = (c4+0 > k) ? av.x - f*pv.x : av.x;
                    av.y = (c4+1 > k) ? av.y - f*pv.y : av.y;
                    av.z = (c4+2 > k) ? av.z - f*pv.z : av.z;
                    av.w = (c4+3 > k) ? av.w - f*pv.w : av.w;
                    *(float4*)(aug + r_*132 + c4) = av;
                }
            }
        }
        __syncthreads();
    }
    if (tid < 64) rds[tid] = 1.0f / aug[tid*132 + tid];
    __syncthreads();
    // T1 = P - K*P  (K[i][m] = Y[m][i] = aug[m][64+i]*rds[m]); store into aug left half
    {
        const int i = tid >> 2, jq = tid & 3;
        float4 tv[4];
#pragma unroll
        for (int q=0;q<4;++q) tv[q] = *(const float4*)(Pl + i*64 + jq*16 + q*4);
        for (int m=0;m<64;++m){
            float kim = aug[m*132 + 64 + i] * rds[m];
#pragma unroll
            for (int q=0;q<4;++q){
                float4 pv = *(const float4*)(Pl + m*64 + jq*16 + q*4);
                tv[q].x -= kim*pv.x; tv[q].y -= kim*pv.y; tv[q].z -= kim*pv.z; tv[q].w -= kim*pv.w;
            }
        }
#pragma unroll
        for (int q=0;q<4;++q) *(float4*)(aug + i*132 + jq*16 + q*4) = tv[q];
    }
    __syncthreads();
    // P_new = T1 - T1*K^T + K*diag(Rd)*K^T ; also emit K
    {
        const int i = tid >> 2, jq = tid & 3;
        float4 a2[4];
#pragma unroll
        for (int q=0;q<4;++q) a2[q] = *(const float4*)(aug + i*132 + jq*16 + q*4);
        for (int m=0;m<64;++m){
            float t1im = aug[i*132 + m];
            float kim  = aug[m*132 + 64 + i] * rds[m];
            float coef = rds[m] * (kim * Rd[m] - t1im);
#pragma unroll
            for (int q=0;q<4;++q){
                float4 yv = *(const float4*)(aug + m*132 + 64 + jq*16 + q*4);
                a2[q].x += coef*yv.x; a2[q].y += coef*yv.y; a2[q].z += coef*yv.z; a2[q].w += coef*yv.w;
            }
        }
        size_t base = ((size_t)b << 12) + (size_t)i*64;
#pragma unroll
        for (int q=0;q<4;++q) *(float4*)(Pg + base + jq*16 + q*4) = a2[q];
#pragma unroll
        for (int q=0;q<4;++q){
#pragma unroll
            for (int e=0;e<4;++e){
                int j = jq*16 + q*4 + e;
                Kg[base + j] = aug[j*132 + 64 + i] * rds[j];
            }
        }
    }
}

// ---------------------------------------------------------------------------
// y_hat = y_tick + K(x0 - y_tick); spatial partial sums for the head.
__global__ __launch_bounds__(256) void k_apply(int t, const float* __restrict__ ytick,
                                               const float* __restrict__ x0, const float* __restrict__ Kg,
                                               float* __restrict__ yhat, float* __restrict__ featpart){
    __shared__ __align__(16) float kt[4096];
    __shared__ float red[4160];
    const int tile = blockIdx.x;
    const int b    = blockIdx.y;
    const int tid  = threadIdx.x;
    const int pj = tid & 63, dg = tid >> 6;

    for (int r = tid; r < 4096; r += 256){
        int i = r >> 6, j = r & 63;
        kt[j*64 + i] = Kg[((size_t)b << 12) + r];
    }
    __syncthreads();

    const int p0 = tile*256 + pj*4;
    float4 acc[16];
#pragma unroll
    for (int i=0;i<16;i++) acc[i] = make_float4(0.f,0.f,0.f,0.f);

    for (int j = 0; j < 64; ++j){
        size_t gi = (((size_t)(b*64 + j)) << 12) + p0;
        float4 xv = *(const float4*)(x0 + gi);
        float4 yv = *(const float4*)(ytick + gi);
        float u0 = xv.x - yv.x, u1 = xv.y - yv.y, u2 = xv.z - yv.z, u3 = xv.w - yv.w;
        const float4* wr = (const float4*)(kt + j*64 + dg*16);
#pragma unroll
        for (int q=0;q<4;++q){
            float4 k4 = wr[q];
            FMA4(acc[q*4+0], k4.x, u0,u1,u2,u3);
            FMA4(acc[q*4+1], k4.y, u0,u1,u2,u3);
            FMA4(acc[q*4+2], k4.z, u0,u1,u2,u3);
            FMA4(acc[q*4+3], k4.w, u0,u1,u2,u3);
        }
    }
    float ls[16];
#pragma unroll
    for (int i=0;i<16;i++){
        int dd = dg*16 + i;
        size_t gi = (((size_t)(b*64 + dd)) << 12) + p0;
        float4 yv = *(const float4*)(ytick + gi);
        float4 o;
        o.x = yv.x + acc[i].x; o.y = yv.y + acc[i].y; o.z = yv.z + acc[i].z; o.w = yv.w + acc[i].w;
        *(float4*)(yhat + gi) = o;
        ls[i] = o.x + o.y + o.z + o.w;
    }
#pragma unroll
    for (int i=0;i<16;i++) red[pj*65 + dg*16 + i] = ls[i];
    __syncthreads();
    if (tid < 64){
        float s = 0.f;
        for (int p=0;p<64;p++) s += red[p*65 + tid];
        featpart[(((size_t)((t*8 + b)*16 + tile)) << 6) + tid] = s;
    }
}

// ---------------------------------------------------------------------------
// Head: feat = relu(fc(ys_mean)); offset/angle. grid 128 (b*16+t), block 64.
__global__ __launch_bounds__(64) void k_head(const float* __restrict__ featpart,
                                             const float* __restrict__ fc_w, const float* __restrict__ fc_b,
                                             const float* __restrict__ fco_w, const float* __restrict__ fco_b,
                                             const float* __restrict__ fca_w, const float* __restrict__ fca_b,
                                             float* __restrict__ out){
    const int bt = blockIdx.x;
    const int b = bt >> 4, t = bt & 15;
    __shared__ float fs[64];
    const int i = threadIdx.x;
    float s = 0.f;
    for (int tile=0;tile<16;tile++) s += featpart[(((size_t)((t*8 + b)*16 + tile)) << 6) + i];
    fs[i] = s * (1.f/4096.f);
    __syncthreads();
    float a = fc_b[i];
    for (int e=0;e<64;e++) a += fc_w[i*64+e]*fs[e];
    a = fmaxf(a, 0.f);
    float po = a * fco_w[i];
    float pa = a * fca_w[i];
    for (int off=32; off; off >>= 1){ po += __shfl_down(po, off); pa += __shfl_down(pa, off); }
    if (i == 0){
        out[bt]       = po + fco_b[0];
        out[128 + bt] = pa + fca_b[0];
    }
}

// ---------------------------------------------------------------------------
extern "C" void kernel_launch(void* const* d_in, const int* in_sizes, int n_in,
                              void* d_out, int out_size, void* d_ws, size_t ws_size,
                              hipStream_t stream){
    const float* x       = (const float*)d_in[0];
    const float* proj_w  = (const float*)d_in[1];
    const float* bn_g    = (const float*)d_in[2];
    const float* bn_b    = (const float*)d_in[3];
    const float* clstm_w = (const float*)d_in[4];
    const float* clstm_b = (const float*)d_in[5];
    const float* lq_wih  = (const float*)d_in[6];
    const float* lq_whh  = (const float*)d_in[7];
    const float* lq_bih  = (const float*)d_in[8];
    const float* lq_bhh  = (const float*)d_in[9];
    const float* lr_wih  = (const float*)d_in[10];
    const float* lr_whh  = (const float*)d_in[11];
    const float* lr_bih  = (const float*)d_in[12];
    const float* lr_bhh  = (const float*)d_in[13];
    const float* fcf_w   = (const float*)d_in[14];
    const float* fcf_b   = (const float*)d_in[15];
    const float* fcF_w   = (const float*)d_in[16];
    const float* fcF_b   = (const float*)d_in[17];
    const float* fcQ_w   = (const float*)d_in[18];
    const float* fcQ_b   = (const float*)d_in[19];
    const float* fcR_w   = (const float*)d_in[20];
    const float* fcR_b   = (const float*)d_in[21];
    const float* P_init  = (const float*)d_in[22];
    const float* fc_w    = (const float*)d_in[23];
    const float* fc_b    = (const float*)d_in[24];
    const float* fco_w   = (const float*)d_in[25];
    const float* fco_b   = (const float*)d_in[26];
    const float* fca_w   = (const float*)d_in[27];
    const float* fca_b   = (const float*)d_in[28];
    float* out = (float*)d_out;
    float* ws  = (float*)d_ws;

    const size_t FIELD = 2097152;        // 8*64*4096
    float* x0     = ws;
    float* yhat   = ws + 1*FIELD;
    float* hfA    = ws + 2*FIELD;
    float* hfB    = ws + 3*FIELD;
    float* cf     = ws + 4*FIELD;
    float* ytick  = ws + 5*FIELD;
    float* w2     = ws + 6*FIELD;        // 294912
    float* psum   = w2 + 294912;         // 131072
    float* psumsq = psum + 131072;       // 131072
    float* scale  = psumsq + 131072;     // 64
    float* shift  = scale + 64;          // 64
    float* xmean  = shift + 64;          // 8192
    float* hfpart = xmean + 8192;        // 32768
    float* ytpart = hfpart + 32768;      // 8192
    float* featpart = ytpart + 8192;     // 131072
    float* hQ     = featpart + 131072;   // 512
    float* cQ     = hQ + 512;
    float* hR     = cQ + 512;
    float* cR     = hR + 512;
    float* Pg     = cR + 512;            // 32768
    float* Kg     = Pg + 32768;          // 32768

    hipLaunchKernelGGL(k_w2, dim3(1152), dim3(256), 0, stream, clstm_w, w2);
    hipLaunchKernelGGL(k_proj, dim3(16,128), dim3(256), 0, stream, x, proj_w, x0, psum, psumsq);
    hipLaunchKernelGGL(k_bnfinal, dim3(1), dim3(64), 0, stream, psum, psumsq, bn_g, bn_b, scale, shift, xmean);
    hipLaunchKernelGGL(k_init, dim3(8192), dim3(256), 0, stream, scale, shift, x0, yhat, hfA, cf, P_init, Pg, hQ, cQ, hR, cR);

    for (int t = 0; t < 16; ++t){
        float* hf_in  = (t & 1) ? hfB : hfA;
        float* hf_out = (t & 1) ? hfA : hfB;
        hipLaunchKernelGGL(k_conv, dim3(64,8), dim3(256), 0, stream,
                           yhat, hf_in, hf_out, cf, w2, clstm_b, hfpart);
        hipLaunchKernelGGL(k_ytick, dim3(16,8), dim3(256), 0, stream,
                           hf_out, fcf_w, fcf_b, ytick, ytpart);
        hipLaunchKernelGGL(k_small, dim3(8), dim3(256), 0, stream, t,
                           hfpart, ytpart, xmean, fcF_w, fcF_b,
                           lq_wih, lq_whh, lq_bih, lq_bhh,
                           lr_wih, lr_whh, lr_bih, lr_bhh,
                           fcQ_w, fcQ_b, fcR_w, fcR_b,
                           hQ, cQ, hR, cR, Pg, Kg);
        hipLaunchKernelGGL(k_apply, dim3(16,8), dim3(256), 0, stream, t,
                           ytick, x0, Kg, yhat, featpart);
    }
    hipLaunchKernelGGL(k_head, dim3(128), dim3(64), 0, stream,
                       featpart, fc_w, fc_b, fco_w, fco_b, fca_w, fca_b, out);
}

// Round 2
// 9589.982 us; speedup vs baseline: 1.0007x; 1.0007x over previous
//
#include <hip/hip_runtime.h>
#include <math.h>

// Problem constants: B=8, S=16, CIN=128, H=W=64, D=64
// N = B*S = 128 conv-batch, P = H*W = 4096 spatial

__device__ __forceinline__ float sigf(float x){ return 1.0f/(1.0f + expf(-x)); }

#define FMA4(A, W, V0, V1, V2, V3) { (A).x += (W)*(V0); (A).y += (W)*(V1); (A).z += (W)*(V2); (A).w += (W)*(V3); }

// ---------------------------------------------------------------------------
// reshape clstm_w (256,128,3,3) -> w2[(ic*9+k)*256 + oc]
__global__ __launch_bounds__(256) void k_w2(const float* __restrict__ cw, float* __restrict__ w2){
    int idx = blockIdx.x*256 + threadIdx.x;
    if (idx < 128*9*256){
        int oc = idx & 255;
        int r  = idx >> 8;           // r = ic*9 + k
        w2[idx] = cw[oc*1152 + r];
    }
}

// ---------------------------------------------------------------------------
// 1x1 proj conv + BN partial sums. Writes raw t==0 slice into x0 buffer.
// grid (16 tiles, 128 n), block 256. Thread: 4 px (float4) x 16 d.
__global__ __launch_bounds__(256) void k_proj(const float* __restrict__ x, const float* __restrict__ pw,
                                              float* __restrict__ x0raw, float* __restrict__ psum,
                                              float* __restrict__ psumsq){
    __shared__ __align__(16) float smem[8192];   // w_lds[c][64], later reduction scratch
    const int tile = blockIdx.x;
    const int n    = blockIdx.y;
    const int tid  = threadIdx.x;
    const int pj = tid & 63, dg = tid >> 6;

    for (int r = tid; r < 8192; r += 256){
        int c = r >> 6, d = r & 63;
        smem[r] = pw[d*128 + c];
    }
    __syncthreads();

    const int p0 = tile*256 + pj*4;
    float4 acc[16];
#pragma unroll
    for (int i=0;i<16;i++) acc[i] = make_float4(0.f,0.f,0.f,0.f);

    const float* xb = x + (((size_t)n) << 19) + p0;
    for (int c = 0; c < 128; ++c){
        float4 xv = *(const float4*)(xb + ((size_t)c << 12));
        const float4* wr = (const float4*)(smem + c*64 + dg*16);
#pragma unroll
        for (int q=0;q<4;++q){
            float4 w4 = wr[q];
            FMA4(acc[q*4+0], w4.x, xv.x, xv.y, xv.z, xv.w);
            FMA4(acc[q*4+1], w4.y, xv.x, xv.y, xv.z, xv.w);
            FMA4(acc[q*4+2], w4.z, xv.x, xv.y, xv.z, xv.w);
            FMA4(acc[q*4+3], w4.w, xv.x, xv.y, xv.z, xv.w);
        }
    }

    const int t = n & 15, b = n >> 4;
    if (t == 0){
#pragma unroll
        for (int i=0;i<16;i++){
            int dd = dg*16 + i;
            *(float4*)(x0raw + (((size_t)(b*64 + dd)) << 12) + p0) = acc[i];
        }
    }
    float ls[16], lss[16];
#pragma unroll
    for (int i=0;i<16;i++){
        float4 a = acc[i];
        ls[i]  = a.x + a.y + a.z + a.w;
        lss[i] = a.x*a.x + a.y*a.y + a.z*a.z + a.w*a.w;
    }
    // deterministic block reduction (pad 65 to avoid bank conflicts)
    __syncthreads();
#pragma unroll
    for (int i=0;i<16;i++) smem[pj*65 + dg*16 + i] = ls[i];
    __syncthreads();
    if (tid < 64){
        float s = 0.f;
        for (int p=0;p<64;p++) s += smem[p*65 + tid];
        psum[((n*16 + tile) << 6) + tid] = s;
    }
    __syncthreads();
#pragma unroll
    for (int i=0;i<16;i++) smem[pj*65 + dg*16 + i] = lss[i];
    __syncthreads();
    if (tid < 64){
        float s = 0.f;
        for (int p=0;p<64;p++) s += smem[p*65 + tid];
        psumsq[((n*16 + tile) << 6) + tid] = s;
    }
}

// ---------------------------------------------------------------------------
// BN finalize: scale/shift per d (fp64 accumulate), and xmean[b][t][d].
__global__ __launch_bounds__(64) void k_bnfinal(const float* __restrict__ psum, const float* __restrict__ psumsq,
                                                const float* __restrict__ gamma, const float* __restrict__ beta,
                                                float* __restrict__ scale, float* __restrict__ shift,
                                                float* __restrict__ xmean){
    const int d = threadIdx.x;
    double gs = 0.0, gss = 0.0;
    for (int n=0;n<128;n++){
        float s = 0.f, ss = 0.f;
        for (int tl=0;tl<16;tl++){
            s  += psum  [((n*16+tl)<<6) + d];
            ss += psumsq[((n*16+tl)<<6) + d];
        }
        gs += (double)s; gss += (double)ss;
    }
    double mu  = gs  / 524288.0;
    double var = gss / 524288.0 - mu*mu;
    double sc  = (double)gamma[d] / sqrt(var + 1e-5);
    float scf = (float)sc;
    float shf = (float)((double)beta[d] - mu*sc);
    scale[d] = scf; shift[d] = shf;
    for (int n=0;n<128;n++){
        float s = 0.f;
        for (int tl=0;tl<16;tl++) s += psum[((n*16+tl)<<6) + d];
        xmean[(n<<6) + d] = (s * (1.f/4096.f)) * scf + shf;
    }
}

// ---------------------------------------------------------------------------
// Apply BN to x0 (in place), init yhat=x0, hfA=0, cf=0, states=0, P=P_init.
__global__ __launch_bounds__(256) void k_init(const float* __restrict__ scale, const float* __restrict__ shift,
                                              float* __restrict__ x0, float* __restrict__ yhat,
                                              float* __restrict__ hfA, float* __restrict__ cf,
                                              const float* __restrict__ Pinit, float* __restrict__ Pg,
                                              float* __restrict__ hQ, float* __restrict__ cQ,
                                              float* __restrict__ hR, float* __restrict__ cR){
    size_t idx = (size_t)blockIdx.x*256 + threadIdx.x;   // 2,097,152 total
    int d = (int)((idx >> 12) & 63);
    float v = x0[idx]*scale[d] + shift[d];
    x0[idx] = v; yhat[idx] = v; hfA[idx] = 0.f; cf[idx] = 0.f;
    if (idx < 512){ hQ[idx]=0.f; cQ[idx]=0.f; hR[idx]=0.f; cR[idx]=0.f; }
    if (idx < 32768) Pg[idx] = Pinit[idx & 4095];
}

// ---------------------------------------------------------------------------
// ConvLSTM step: zc = conv3x3([yhat, hf_in]) + b; gates -> cf (in place), hf_out.
// grid (64 rows, 8 b), block 256. smem: 64KB union {w[4][9][256]+in[4][3][66] | zc[64px][256oc]}.
__global__ __launch_bounds__(256) void k_conv(const float* __restrict__ yhat, const float* __restrict__ hf_in,
                                              float* __restrict__ hf_out, float* __restrict__ cf,
                                              const float* __restrict__ w2, const float* __restrict__ cb,
                                              float* __restrict__ hfpart){
    __shared__ __align__(16) float smem[16384];
    const int row = blockIdx.x;
    const int b   = blockIdx.y;
    const int tid = threadIdx.x;
    const int pxq = tid & 15;     // 4 px each
    const int ocq = tid >> 4;     // 16 oc each
    const int IN_OFF = 9216;

    float4 acc[16];
#pragma unroll
    for (int i=0;i<16;i++) acc[i] = make_float4(0.f,0.f,0.f,0.f);

    for (int icc = 0; icc < 32; ++icc){
        __syncthreads();
        {   // stage 4 ic of weights: contiguous copy, [icl][k][oc]
            const float4* src = (const float4*)(w2 + (size_t)icc*9216);
            float4* dst = (float4*)(smem);
            for (int r = tid; r < 2304; r += 256) dst[r] = src[r];
        }
        for (int r = tid; r < 792; r += 256){   // 4 ic x 3 dy x 66 xi
            int icl = r / 198; int rem = r - icl*198;
            int dy  = rem / 66; int xi = rem - dy*66;
            int icg = icc*4 + icl;
            int yy = row + dy - 1;
            int xx = xi - 1;
            float v = 0.f;
            if (yy >= 0 && yy < 64 && xx >= 0 && xx < 64){
                const float* src = (icg < 64) ? yhat : hf_in;
                v = src[(((size_t)(b*64 + (icg & 63))) << 12) + yy*64 + xx];
            }
            smem[IN_OFF + r] = v;
        }
        __syncthreads();
#pragma unroll
        for (int icl = 0; icl < 4; ++icl){
            float v[3][6];
#pragma unroll
            for (int dy=0; dy<3; ++dy)
#pragma unroll
                for (int j=0;j<6;++j)
                    v[dy][j] = smem[IN_OFF + icl*198 + dy*66 + pxq*4 + j];
#pragma unroll
            for (int k=0;k<9;++k){
                const int ky = k/3, kx = k - ky*3;
                const float4* wr = (const float4*)(smem + (icl*9+k)*256 + ocq*16);
                const float v0=v[ky][kx+0], v1=v[ky][kx+1], v2=v[ky][kx+2], v3=v[ky][kx+3];
#pragma unroll
                for (int q=0;q<4;++q){
                    float4 w4 = wr[q];
                    FMA4(acc[q*4+0], w4.x, v0,v1,v2,v3);
                    FMA4(acc[q*4+1], w4.y, v0,v1,v2,v3);
                    FMA4(acc[q*4+2], w4.z, v0,v1,v2,v3);
                    FMA4(acc[q*4+3], w4.w, v0,v1,v2,v3);
                }
            }
        }
    }

    // write zc (+bias) to LDS, layout [px][256 oc]
    __syncthreads();
#pragma unroll
    for (int i=0;i<16;i++){
        int oc = ocq*16 + i;
        float bv = cb[oc];
        int px0 = pxq*4;
        smem[(px0+0)*256 + oc] = acc[i].x + bv;
        smem[(px0+1)*256 + oc] = acc[i].y + bv;
        smem[(px0+2)*256 + oc] = acc[i].z + bv;
        smem[(px0+3)*256 + oc] = acc[i].w + bv;
    }
    __syncthreads();

    // gating: i,f,o,g order. thread: d = tid&63, 16 px.
    const int d   = tid & 63;
    const int pxg = tid >> 6;
    float hsum = 0.f;
#pragma unroll
    for (int jq=0; jq<4; ++jq){
        int px0 = pxg*16 + jq*4;
        float zi0 = smem[(px0+0)*256 + d],       zi1 = smem[(px0+1)*256 + d],       zi2 = smem[(px0+2)*256 + d],       zi3 = smem[(px0+3)*256 + d];
        float zf0 = smem[(px0+0)*256 + 64 + d],  zf1 = smem[(px0+1)*256 + 64 + d],  zf2 = smem[(px0+2)*256 + 64 + d],  zf3 = smem[(px0+3)*256 + 64 + d];
        float zo0 = smem[(px0+0)*256 + 128 + d], zo1 = smem[(px0+1)*256 + 128 + d], zo2 = smem[(px0+2)*256 + 128 + d], zo3 = smem[(px0+3)*256 + 128 + d];
        float zg0 = smem[(px0+0)*256 + 192 + d], zg1 = smem[(px0+1)*256 + 192 + d], zg2 = smem[(px0+2)*256 + 192 + d], zg3 = smem[(px0+3)*256 + 192 + d];
        size_t gidx = (((size_t)(b*64 + d)) << 12) + row*64 + px0;
        float4 c_old = *(const float4*)(cf + gidx);
        float4 c2, h;
        c2.x = sigf(zf0)*c_old.x + sigf(zi0)*tanhf(zg0); h.x = sigf(zo0)*tanhf(c2.x);
        c2.y = sigf(zf1)*c_old.y + sigf(zi1)*tanhf(zg1); h.y = sigf(zo1)*tanhf(c2.y);
        c2.z = sigf(zf2)*c_old.z + sigf(zi2)*tanhf(zg2); h.z = sigf(zo2)*tanhf(c2.z);
        c2.w = sigf(zf3)*c_old.w + sigf(zi3)*tanhf(zg3); h.w = sigf(zo3)*tanhf(c2.w);
        *(float4*)(cf + gidx) = c2;
        *(float4*)(hf_out + gidx) = h;
        hsum += h.x + h.y + h.z + h.w;
    }
    __syncthreads();
    smem[pxg*64 + d] = hsum;
    __syncthreads();
    if (tid < 64){
        float s = smem[tid] + smem[64+tid] + smem[128+tid] + smem[192+tid];
        hfpart[((b*64 + row) << 6) + tid] = s;
    }
}

// ---------------------------------------------------------------------------
// y_tick = fcf(hf) per position + spatial partial sums. grid (16,8), block 256.
__global__ __launch_bounds__(256) void k_ytick(const float* __restrict__ hf, const float* __restrict__ fw,
                                               const float* __restrict__ fb, float* __restrict__ ytick,
                                               float* __restrict__ ytpart){
    __shared__ __align__(16) float wsm[4096];
    __shared__ float red[4160];
    const int tile = blockIdx.x;
    const int b    = blockIdx.y;
    const int tid  = threadIdx.x;
    const int pj = tid & 63, dg = tid >> 6;

    for (int r = tid; r < 4096; r += 256){
        int e = r >> 6, dd = r & 63;
        wsm[r] = fw[dd*64 + e];
    }
    __syncthreads();

    const int p0 = tile*256 + pj*4;
    float4 acc[16];
#pragma unroll
    for (int i=0;i<16;i++) acc[i] = make_float4(0.f,0.f,0.f,0.f);

    const float* hb = hf + (((size_t)b) << 18) + p0;
    for (int e = 0; e < 64; ++e){
        float4 hv = *(const float4*)(hb + ((size_t)e << 12));
        const float4* wr = (const float4*)(wsm + e*64 + dg*16);
#pragma unroll
        for (int q=0;q<4;++q){
            float4 w4 = wr[q];
            FMA4(acc[q*4+0], w4.x, hv.x, hv.y, hv.z, hv.w);
            FMA4(acc[q*4+1], w4.y, hv.x, hv.y, hv.z, hv.w);
            FMA4(acc[q*4+2], w4.z, hv.x, hv.y, hv.z, hv.w);
            FMA4(acc[q*4+3], w4.w, hv.x, hv.y, hv.z, hv.w);
        }
    }
    float ls[16];
#pragma unroll
    for (int i=0;i<16;i++){
        int dd = dg*16 + i;
        float bv = fb[dd];
        acc[i].x += bv; acc[i].y += bv; acc[i].z += bv; acc[i].w += bv;
        *(float4*)(ytick + (((size_t)(b*64 + dd)) << 12) + p0) = acc[i];
        ls[i] = acc[i].x + acc[i].y + acc[i].z + acc[i].w;
    }
#pragma unroll
    for (int i=0;i<16;i++) red[pj*65 + dg*16 + i] = ls[i];
    __syncthreads();
    if (tid < 64){
        float s = 0.f;
        for (int p=0;p<64;p++) s += red[p*65 + tid];
        ytpart[((b*16 + tile) << 6) + tid] = s;
    }
}

// ---------------------------------------------------------------------------
// Per-step small ops + Kalman update. grid 8 (b), block 256.
__global__ __launch_bounds__(256) void k_small(int t,
        const float* __restrict__ hfpart, const float* __restrict__ ytpart, const float* __restrict__ xmean,
        const float* __restrict__ fcF_w, const float* __restrict__ fcF_b,
        const float* __restrict__ lq_wih, const float* __restrict__ lq_whh,
        const float* __restrict__ lq_bih, const float* __restrict__ lq_bhh,
        const float* __restrict__ lr_wih, const float* __restrict__ lr_whh,
        const float* __restrict__ lr_bih, const float* __restrict__ lr_bhh,
        const float* __restrict__ fcQ_w, const float* __restrict__ fcQ_b,
        const float* __restrict__ fcR_w, const float* __restrict__ fcR_b,
        float* __restrict__ hQ, float* __restrict__ cQ, float* __restrict__ hR, float* __restrict__ cR,
        float* __restrict__ Pg, float* __restrict__ Kg){
    const int b = blockIdx.x, tid = threadIdx.x;
    __shared__ __align__(16) float aug[64*132];
    __shared__ __align__(16) float Pl[4096];
    __shared__ float hfm[64], ytm[64], xm[64], Fv[64], Qd[64], Rd[64], rds[64];
    __shared__ float hq_s[64], cq_s[64], hr_s[64], cr_s[64];
    __shared__ float gq[256], gr[256];

    if (tid < 64){
        float s = 0.f;
        for (int r=0;r<64;r++) s += hfpart[((b*64 + r) << 6) + tid];
        hfm[tid] = s * (1.f/4096.f);
        float s2 = 0.f;
        for (int r=0;r<16;r++) s2 += ytpart[((b*16 + r) << 6) + tid];
        ytm[tid] = s2 * (1.f/4096.f);
        xm[tid] = xmean[((b*16 + t) << 6) + tid];
        hq_s[tid] = hQ[b*64+tid]; cq_s[tid] = cQ[b*64+tid];
        hr_s[tid] = hR[b*64+tid]; cr_s[tid] = cR[b*64+tid];
    }
    __syncthreads();
    {   // LSTM gate pre-activations (all 256 threads) + Fv (first 64)
        int j = tid;
        float aq = lq_bih[j] + lq_bhh[j];
        float ar = lr_bih[j] + lr_bhh[j];
        for (int e=0;e<64;e++){
            aq += lq_wih[j*64+e]*ytm[e] + lq_whh[j*64+e]*hq_s[e];
            ar += lr_wih[j*64+e]*xm[e]  + lr_whh[j*64+e]*hr_s[e];
        }
        gq[j] = aq; gr[j] = ar;
    }
    if (tid < 64){
        float a = fcF_b[tid];
        for (int e=0;e<64;e++) a += fcF_w[tid*64+e]*hfm[e];
        Fv[tid] = a;
    }
    __syncthreads();
    if (tid < 64){   // lstm_cell gate order: i, f, g, o
        int dd = tid;
        float gi = gq[dd], gf = gq[64+dd], gg = gq[128+dd], go = gq[192+dd];
        float c2 = sigf(gf)*cq_s[dd] + sigf(gi)*tanhf(gg);
        float h2 = sigf(go)*tanhf(c2);
        cq_s[dd] = c2; hq_s[dd] = h2;
        gi = gr[dd]; gf = gr[64+dd]; gg = gr[128+dd]; go = gr[192+dd];
        c2 = sigf(gf)*cr_s[dd] + sigf(gi)*tanhf(gg);
        h2 = sigf(go)*tanhf(c2);
        cr_s[dd] = c2; hr_s[dd] = h2;
    }
    __syncthreads();
    if (tid < 64){
        float aq_ = fcQ_b[tid], ar_ = fcR_b[tid];
        for (int e=0;e<64;e++){ aq_ += fcQ_w[tid*64+e]*hq_s[e]; ar_ += fcR_w[tid*64+e]*hr_s[e]; }
        Qd[tid] = expf(aq_); Rd[tid] = expf(ar_);
        hQ[b*64+tid] = hq_s[tid]; cQ[b*64+tid] = cq_s[tid];
        hR[b*64+tid] = hr_s[tid]; cR[b*64+tid] = cr_s[tid];
    }
    __syncthreads();
    // P = P*FF + diag(Qd); aug = [A=P+diag(Rd) | P]
    for (int r = tid; r < 4096; r += 256){
        int i = r >> 6, j = r & 63;
        float p = Pg[((size_t)b << 12) + r] * Fv[i]*Fv[j] + (i==j ? Qd[i] : 0.f);
        Pl[r] = p;
        aug[i*132 + 64 + j] = p;
        aug[i*132 + j]      = p + (i==j ? Rd[i] : 0.f);
    }
    __syncthreads();
    // Gauss-Jordan, no pivot-row scaling, only cols > k touched (race-free, 1 barrier/iter)
    const int r_ = tid & 63, cq_ = tid >> 6;
    for (int k = 0; k < 64; ++k){
        float akk = aug[k*132 + k];
        float f = aug[r_*132 + k] / akk;
        if (r_ != k){
#pragma unroll
            for (int u = 0; u < 8; ++u){
                int c4 = cq_*32 + u*4;
                if (c4 + 3 > k){
                    float4 pv = *(const float4*)(aug + k*132 + c4);
                    float4 av = *(const float4*)(aug + r_*132 + c4);
                    av.x = (c4+0 > k) ? av.x - f*pv.x : av.x;
                    av.y = (c4+1 > k) ? av.y - f*pv.y : av.y;
                    av.z = (c4+2 > k) ? av.z - f*pv.z : av.z;
                    av.w = (c4+3 > k) ? av.w - f*pv.w : av.w;
                    *(float4*)(aug + r_*132 + c4) = av;
                }
            }
        }
        __syncthreads();
    }
    if (tid < 64) rds[tid] = 1.0f / aug[tid*132 + tid];
    __syncthreads();
    // T1 = P - K*P  (K[i][m] = Y[m][i] = aug[m][64+i]*rds[m]); store into aug left half
    {
        const int i = tid >> 2, jq = tid & 3;
        float4 tv[4];
#pragma unroll
        for (int q=0;q<4;++q) tv[q] = *(const float4*)(Pl + i*64 + jq*16 + q*4);
        for (int m=0;m<64;++m){
            float kim = aug[m*132 + 64 + i] * rds[m];
#pragma unroll
            for (int q=0;q<4;++q){
                float4 pv = *(const float4*)(Pl + m*64 + jq*16 + q*4);
                tv[q].x -= kim*pv.x; tv[q].y -= kim*pv.y; tv[q].z -= kim*pv.z; tv[q].w -= kim*pv.w;
            }
        }
#pragma unroll
        for (int q=0;q<4;++q) *(float4*)(aug + i*132 + jq*16 + q*4) = tv[q];
    }
    __syncthreads();
    // P_new = T1 - T1*K^T + K*diag(Rd)*K^T ; also emit K
    {
        const int i = tid >> 2, jq = tid & 3;
        float4 a2[4];
#pragma unroll
        for (int q=0;q<4;++q) a2[q] = *(const float4*)(aug + i*132 + jq*16 + q*4);
        for (int m=0;m<64;++m){
            float t1im = aug[i*132 + m];
            float kim  = aug[m*132 + 64 + i] * rds[m];
            float coef = rds[m] * (kim * Rd[m] - t1im);
#pragma unroll
            for (int q=0;q<4;++q){
                float4 yv = *(const float4*)(aug + m*132 + 64 + jq*16 + q*4);
                a2[q].x += coef*yv.x; a2[q].y += coef*yv.y; a2[q].z += coef*yv.z; a2[q].w += coef*yv.w;
            }
        }
        size_t base = ((size_t)b << 12) + (size_t)i*64;
#pragma unroll
        for (int q=0;q<4;++q) *(float4*)(Pg + base + jq*16 + q*4) = a2[q];
#pragma unroll
        for (int q=0;q<4;++q){
#pragma unroll
            for (int e=0;e<4;++e){
                int j = jq*16 + q*4 + e;
                Kg[base + j] = aug[j*132 + 64 + i] * rds[j];
            }
        }
    }
}

// ---------------------------------------------------------------------------
// y_hat = y_tick + K(x0 - y_tick); spatial partial sums for the head.
__global__ __launch_bounds__(256) void k_apply(int t, const float* __restrict__ ytick,
                                               const float* __restrict__ x0, const float* __restrict__ Kg,
                                               float* __restrict__ yhat, float* __restrict__ featpart){
    __shared__ __align__(16) float kt[4096];
    __shared__ float red[4160];
    const int tile = blockIdx.x;
    const int b    = blockIdx.y;
    const int tid  = threadIdx.x;
    const int pj = tid & 63, dg = tid >> 6;

    for (int r = tid; r < 4096; r += 256){
        int i = r >> 6, j = r & 63;
        kt[j*64 + i] = Kg[((size_t)b << 12) + r];
    }
    __syncthreads();

    const int p0 = tile*256 + pj*4;
    float4 acc[16];
#pragma unroll
    for (int i=0;i<16;i++) acc[i] = make_float4(0.f,0.f,0.f,0.f);

    for (int j = 0; j < 64; ++j){
        size_t gi = (((size_t)(b*64 + j)) << 12) + p0;
        float4 xv = *(const float4*)(x0 + gi);
        float4 yv = *(const float4*)(ytick + gi);
        float u0 = xv.x - yv.x, u1 = xv.y - yv.y, u2 = xv.z - yv.z, u3 = xv.w - yv.w;
        const float4* wr = (const float4*)(kt + j*64 + dg*16);
#pragma unroll
        for (int q=0;q<4;++q){
            float4 k4 = wr[q];
            FMA4(acc[q*4+0], k4.x, u0,u1,u2,u3);
            FMA4(acc[q*4+1], k4.y, u0,u1,u2,u3);
            FMA4(acc[q*4+2], k4.z, u0,u1,u2,u3);
            FMA4(acc[q*4+3], k4.w, u0,u1,u2,u3);
        }
    }
    float ls[16];
#pragma unroll
    for (int i=0;i<16;i++){
        int dd = dg*16 + i;
        size_t gi = (((size_t)(b*64 + dd)) << 12) + p0;
        float4 yv = *(const float4*)(ytick + gi);
        float4 o;
        o.x = yv.x + acc[i].x; o.y = yv.y + acc[i].y; o.z = yv.z + acc[i].z; o.w = yv.w + acc[i].w;
        *(float4*)(yhat + gi) = o;
        ls[i] = o.x + o.y + o.z + o.w;
    }
#pragma unroll
    for (int i=0;i<16;i++) red[pj*65 + dg*16 + i] = ls[i];
    __syncthreads();
    if (tid < 64){
        float s = 0.f;
        for (int p=0;p<64;p++) s += red[p*65 + tid];
        featpart[(((size_t)((t*8 + b)*16 + tile)) << 6) + tid] = s;
    }
}

// ---------------------------------------------------------------------------
// Head: feat = relu(fc(ys_mean)); offset/angle. grid 128 (b*16+t), block 64.
__global__ __launch_bounds__(64) void k_head(const float* __restrict__ featpart,
                                             const float* __restrict__ fc_w, const float* __restrict__ fc_b,
                                             const float* __restrict__ fco_w, const float* __restrict__ fco_b,
                                             const float* __restrict__ fca_w, const float* __restrict__ fca_b,
                                             float* __restrict__ out){
    const int bt = blockIdx.x;
    const int b = bt >> 4, t = bt & 15;
    __shared__ float fs[64];
    const int i = threadIdx.x;
    float s = 0.f;
    for (int tile=0;tile<16;tile++) s += featpart[(((size_t)((t*8 + b)*16 + tile)) << 6) + i];
    fs[i] = s * (1.f/4096.f);
    __syncthreads();
    float a = fc_b[i];
    for (int e=0;e<64;e++) a += fc_w[i*64+e]*fs[e];
    a = fmaxf(a, 0.f);
    float po = a * fco_w[i];
    float pa = a * fca_w[i];
    for (int off=32; off; off >>= 1){ po += __shfl_down(po, off); pa += __shfl_down(pa, off); }
    if (i == 0){
        out[bt]       = po + fco_b[0];
        out[128 + bt] = pa + fca_b[0];
    }
}

// ---------------------------------------------------------------------------
extern "C" void kernel_launch(void* const* d_in, const int* in_sizes, int n_in,
                              void* d_out, int out_size, void* d_ws, size_t ws_size,
                              hipStream_t stream){
    const float* x       = (const float*)d_in[0];
    const float* proj_w  = (const float*)d_in[1];
    const float* bn_g    = (const float*)d_in[2];
    const float* bn_b    = (const float*)d_in[3];
    const float* clstm_w = (const float*)d_in[4];
    const float* clstm_b = (const float*)d_in[5];
    const float* lq_wih  = (const float*)d_in[6];
    const float* lq_whh  = (const float*)d_in[7];
    const float* lq_bih  = (const float*)d_in[8];
    const float* lq_bhh  = (const float*)d_in[9];
    const float* lr_wih  = (const float*)d_in[10];
    const float* lr_whh  = (const float*)d_in[11];
    const float* lr_bih  = (const float*)d_in[12];
    const float* lr_bhh  = (const float*)d_in[13];
    const float* fcf_w   = (const float*)d_in[14];
    const float* fcf_b   = (const float*)d_in[15];
    const float* fcF_w   = (const float*)d_in[16];
    const float* fcF_b   = (const float*)d_in[17];
    const float* fcQ_w   = (const float*)d_in[18];
    const float* fcQ_b   = (const float*)d_in[19];
    const float* fcR_w   = (const float*)d_in[20];
    const float* fcR_b   = (const float*)d_in[21];
    const float* P_init  = (const float*)d_in[22];
    const float* fc_w    = (const float*)d_in[23];
    const float* fc_b    = (const float*)d_in[24];
    const float* fco_w   = (const float*)d_in[25];
    const float* fco_b   = (const float*)d_in[26];
    const float* fca_w   = (const float*)d_in[27];
    const float* fca_b   = (const float*)d_in[28];
    float* out = (float*)d_out;
    float* ws  = (float*)d_ws;

    const size_t FIELD = 2097152;        // 8*64*4096
    float* x0     = ws;
    float* yhat   = ws + 1*FIELD;
    float* hfA    = ws + 2*FIELD;
    float* hfB    = ws + 3*FIELD;
    float* cf     = ws + 4*FIELD;
    float* ytick  = ws + 5*FIELD;
    float* w2     = ws + 6*FIELD;        // 294912
    float* psum   = w2 + 294912;         // 131072
    float* psumsq = psum + 131072;       // 131072
    float* scale  = psumsq + 131072;     // 64
    float* shift  = scale + 64;          // 64
    float* xmean  = shift + 64;          // 8192
    float* hfpart = xmean + 8192;        // 32768
    float* ytpart = hfpart + 32768;      // 8192
    float* featpart = ytpart + 8192;     // 131072
    float* hQ     = featpart + 131072;   // 512
    float* cQ     = hQ + 512;
    float* hR     = cQ + 512;
    float* cR     = hR + 512;
    float* Pg     = cR + 512;            // 32768
    float* Kg     = Pg + 32768;          // 32768

    hipLaunchKernelGGL(k_w2, dim3(1152), dim3(256), 0, stream, clstm_w, w2);
    hipLaunchKernelGGL(k_proj, dim3(16,128), dim3(256), 0, stream, x, proj_w, x0, psum, psumsq);
    hipLaunchKernelGGL(k_bnfinal, dim3(1), dim3(64), 0, stream, psum, psumsq, bn_g, bn_b, scale, shift, xmean);
    hipLaunchKernelGGL(k_init, dim3(8192), dim3(256), 0, stream, scale, shift, x0, yhat, hfA, cf, P_init, Pg, hQ, cQ, hR, cR);

    for (int t = 0; t < 16; ++t){
        float* hf_in  = (t & 1) ? hfB : hfA;
        float* hf_out = (t & 1) ? hfA : hfB;
        hipLaunchKernelGGL(k_conv, dim3(64,8), dim3(256), 0, stream,
                           yhat, hf_in, hf_out, cf, w2, clstm_b, hfpart);
        hipLaunchKernelGGL(k_ytick, dim3(16,8), dim3(256), 0, stream,
                           hf_out, fcf_w, fcf_b, ytick, ytpart);
        hipLaunchKernelGGL(k_small, dim3(8), dim3(256), 0, stream, t,
                           hfpart, ytpart, xmean, fcF_w, fcF_b,
                           lq_wih, lq_whh, lq_bih, lq_bhh,
                           lr_wih, lr_whh, lr_bih, lr_bhh,
                           fcQ_w, fcQ_b, fcR_w, fcR_b,
                           hQ, cQ, hR, cR, Pg, Kg);
        hipLaunchKernelGGL(k_apply, dim3(16,8), dim3(256), 0, stream, t,
                           ytick, x0, Kg, yhat, featpart);
    }
    hipLaunchKernelGGL(k_head, dim3(128), dim3(64), 0, stream,
                       featpart, fc_w, fc_b, fco_w, fco_b, fca_w, fca_b, out);
}